// Round 2
// baseline (243.152 us; speedup 1.0000x reference)
//
#include <hip/hip_runtime.h>
#include <hip/hip_bf16.h>

#define N 8192
#define OD 64
#define E_EDGES 262144

#define BM 64
#define KSPLIT 8
#define KS_PER_SPLIT (N / KSPLIT)   // 1024

typedef __attribute__((ext_vector_type(8))) short bf16x8;
typedef __attribute__((ext_vector_type(4))) float f32x4;

__device__ __forceinline__ unsigned short f2bf(float f) {
    union { float f; unsigned u; } v; v.f = f;
    unsigned r = (v.u + 0x7fffu + ((v.u >> 16) & 1u)) >> 16;  // RNE
    return (unsigned short)r;
}

// ---------------- sum of squares of attn -> ws[0] ----------------
__global__ __launch_bounds__(256) void norm_sq_kernel(const float* __restrict__ attn,
                                                      float* __restrict__ ws) {
    const float4* a4 = (const float4*)attn;
    const int total = (N * (long)N) / 4;
    float s = 0.f;
    for (long i = (long)blockIdx.x * blockDim.x + threadIdx.x; i < total;
         i += (long)gridDim.x * blockDim.x) {
        float4 v = a4[i];
        s += v.x * v.x + v.y * v.y + v.z * v.z + v.w * v.w;
    }
    for (int off = 32; off > 0; off >>= 1) s += __shfl_down(s, off, 64);
    __shared__ float wpart[4];
    int wid = threadIdx.x >> 6;
    if ((threadIdx.x & 63) == 0) wpart[wid] = s;
    __syncthreads();
    if (threadIdx.x == 0) atomicAdd(ws, wpart[0] + wpart[1] + wpart[2] + wpart[3]);
}

// ---------------- convert W [N][OD] f32 -> wt [OD][N] bf16 (transposed) ----------------
__global__ __launch_bounds__(256) void convert_w_kernel(const float* __restrict__ w,
                                                        unsigned short* __restrict__ wt) {
    // i: col-major over wt so writes are coalesced; reads are 4B-scattered but
    // the 2MB source is L2-resident after first touch.
    int i = blockIdx.x * 256 + threadIdx.x;   // 0 .. 524287
    int col = i >> 13;                        // /8192
    int k = i & 8191;
    wt[i] = f2bf(w[k * OD + col]);
}

// ---------------- y_part[split] = x[:, ksplit] @ W[ksplit, :] — register-only MFMA ----------------
__global__ __launch_bounds__(256) void gemm_kernel(const float* __restrict__ x,
                                                   const unsigned short* __restrict__ wt,
                                                   float* __restrict__ y_part) {
    const int tid = threadIdx.x;
    const int wv = tid >> 6;
    const int lane = tid & 63;
    const int lrow = lane & 15;   // A-row / B-col within 16x16 fragment
    const int g = lane >> 4;      // k-group (8 elems each)
    const int row = blockIdx.x * BM + wv * 16 + lrow;
    const int split = blockIdx.y;
    const int k0 = split * KS_PER_SPLIT;

    f32x4 acc[4] = {f32x4{0,0,0,0}, f32x4{0,0,0,0}, f32x4{0,0,0,0}, f32x4{0,0,0,0}};

    const float* xp = x + (size_t)row * N + k0 + g * 8;
    const unsigned short* wp = wt + k0 + g * 8;

    #pragma unroll 4
    for (int ks = 0; ks < KS_PER_SPLIT / 32; ++ks) {   // 32 iters
        float4 v0 = *(const float4*)(xp + ks * 32);
        float4 v1 = *(const float4*)(xp + ks * 32 + 4);
        bf16x8 a;
        a[0] = f2bf(v0.x); a[1] = f2bf(v0.y); a[2] = f2bf(v0.z); a[3] = f2bf(v0.w);
        a[4] = f2bf(v1.x); a[5] = f2bf(v1.y); a[6] = f2bf(v1.z); a[7] = f2bf(v1.w);
        #pragma unroll
        for (int cf = 0; cf < 4; ++cf) {
            bf16x8 b = *(const bf16x8*)(wp + (size_t)(cf * 16 + lrow) * N + ks * 32);
            acc[cf] = __builtin_amdgcn_mfma_f32_16x16x32_bf16(a, b, acc[cf], 0, 0, 0);
        }
    }
    // C/D layout: col = lane&15, row = (lane>>4)*4 + i (verified)
    float* yp = y_part + (size_t)split * N * OD + ((size_t)blockIdx.x * BM + wv * 16 + g * 4) * OD;
    #pragma unroll
    for (int cf = 0; cf < 4; ++cf) {
        #pragma unroll
        for (int i = 0; i < 4; ++i) {
            yp[i * OD + cf * 16 + lrow] = acc[cf][i];
        }
    }
}

// ---------------- y = sum over splits of y_part ----------------
__global__ __launch_bounds__(256) void reduce_y_kernel(const float4* __restrict__ y_part,
                                                       float4* __restrict__ y) {
    int i = blockIdx.x * 256 + threadIdx.x;   // 0 .. 131071 (N*OD/4)
    const int stride = N * OD / 4;
    float4 s = y_part[i];
    #pragma unroll
    for (int p = 1; p < KSPLIT; ++p) {
        float4 v = y_part[p * stride + i];
        s.x += v.x; s.y += v.y; s.z += v.z; s.w += v.w;
    }
    y[i] = s;
}

// ---------------- edge scatter: out[row[e]] += values[e]*attn[row,col] * y[col[e]] ----------------
__global__ __launch_bounds__(256) void scatter_kernel(const float* __restrict__ values,
                                                      const float* __restrict__ attn,
                                                      const int* __restrict__ row,
                                                      const int* __restrict__ col,
                                                      const float* __restrict__ y,
                                                      float* __restrict__ out) {
    const int e = blockIdx.x * 4 + (threadIdx.x >> 6);
    const int lane = threadIdx.x & 63;
    const int r = row[e];
    const int c = col[e];
    const float ev = values[e] * attn[(size_t)r * N + c];
    atomicAdd(&out[r * OD + lane], ev * y[c * OD + lane]);
}

__global__ void finalize_kernel(const float* __restrict__ ws, float* __restrict__ out_norm) {
    if (threadIdx.x == 0) *out_norm = sqrtf(ws[0]);
}

extern "C" void kernel_launch(void* const* d_in, const int* in_sizes, int n_in,
                              void* d_out, int out_size, void* d_ws, size_t ws_size,
                              hipStream_t stream) {
    const float* x      = (const float*)d_in[0];
    const float* attn   = (const float*)d_in[1];
    const float* weight = (const float*)d_in[2];
    const float* values = (const float*)d_in[3];
    const int*   row    = (const int*)d_in[4];
    const int*   col    = (const int*)d_in[5];
    float* out = (float*)d_out;

    char* wsb = (char*)d_ws;
    float*          norm_acc = (float*)wsb;                         // 4 B
    unsigned short* wt       = (unsigned short*)(wsb + 256);        // 1 MB
    float*          y        = (float*)(wsb + 256 + (1u << 20));    // 2 MB
    float*          y_part   = (float*)(wsb + 256 + (1u << 20) + (2u << 20)); // 16 MB

    hipMemsetAsync(d_out, 0, (size_t)out_size * sizeof(float), stream);  // atomic target
    hipMemsetAsync(d_ws, 0, 256, stream);                                // norm accumulator

    convert_w_kernel<<<2048, 256, 0, stream>>>(weight, wt);
    gemm_kernel<<<dim3(N / BM, KSPLIT), 256, 0, stream>>>(x, wt, y_part);
    reduce_y_kernel<<<N * OD / 4 / 256, 256, 0, stream>>>((const float4*)y_part, (float4*)y);
    norm_sq_kernel<<<2048, 256, 0, stream>>>(attn, norm_acc);
    scatter_kernel<<<E_EDGES / 4, 256, 0, stream>>>(values, attn, row, col, y, out);
    finalize_kernel<<<1, 64, 0, stream>>>(norm_acc, out + (size_t)N * OD);
}

// Round 3
// 217.184 us; speedup vs baseline: 1.1196x; 1.1196x over previous
//
#include <hip/hip_runtime.h>
#include <hip/hip_bf16.h>

#define N 8192
#define OD 64
#define E_EDGES 262144

#define BM 64
#define KSPLIT 8
#define KS_PER_SPLIT (N / KSPLIT)   // 1024
#define NORM_BLOCKS 2048

typedef __attribute__((ext_vector_type(8))) short bf16x8;
typedef __attribute__((ext_vector_type(4))) float f32x4;

__device__ __forceinline__ unsigned short f2bf(float f) {
    union { float f; unsigned u; } v; v.f = f;
    unsigned r = (v.u + 0x7fffu + ((v.u >> 16) & 1u)) >> 16;  // RNE
    return (unsigned short)r;
}

// ---------------- sum of squares of attn -> per-block partials (no init needed) ----------------
__global__ __launch_bounds__(256) void norm_sq_kernel(const float* __restrict__ attn,
                                                      float* __restrict__ part) {
    const float4* a4 = (const float4*)attn;
    const int total = (N * (long)N) / 4;
    float s = 0.f;
    for (long i = (long)blockIdx.x * blockDim.x + threadIdx.x; i < total;
         i += (long)NORM_BLOCKS * blockDim.x) {
        float4 v = a4[i];
        s += v.x * v.x + v.y * v.y + v.z * v.z + v.w * v.w;
    }
    for (int off = 32; off > 0; off >>= 1) s += __shfl_down(s, off, 64);
    __shared__ float wpart[4];
    int wid = threadIdx.x >> 6;
    if ((threadIdx.x & 63) == 0) wpart[wid] = s;
    __syncthreads();
    if (threadIdx.x == 0) part[blockIdx.x] = wpart[0] + wpart[1] + wpart[2] + wpart[3];
}

// ---------------- convert W [N][OD] f32 -> wt [OD][N] bf16 (transposed), and zero d_out ----------------
__global__ __launch_bounds__(256) void convert_w_kernel(const float* __restrict__ w,
                                                        unsigned short* __restrict__ wt,
                                                        float4* __restrict__ out4) {
    int i = blockIdx.x * 256 + threadIdx.x;   // 0 .. 524287
    int col = i >> 13;                        // /8192
    int k = i & 8191;
    wt[i] = f2bf(w[k * OD + col]);
    if (i < (N * OD / 4)) out4[i] = float4{0.f, 0.f, 0.f, 0.f};  // zero scatter target
}

// ---------------- y_part[split] = x[:, ksplit] @ W[ksplit, :] — register-only MFMA ----------------
__global__ __launch_bounds__(256) void gemm_kernel(const float* __restrict__ x,
                                                   const unsigned short* __restrict__ wt,
                                                   float* __restrict__ y_part) {
    const int tid = threadIdx.x;
    const int wv = tid >> 6;
    const int lane = tid & 63;
    const int lrow = lane & 15;   // A-row / B-col within 16x16 fragment
    const int g = lane >> 4;      // k-group (8 elems each)
    const int row = blockIdx.x * BM + wv * 16 + lrow;
    const int split = blockIdx.y;
    const int k0 = split * KS_PER_SPLIT;

    f32x4 acc[4] = {f32x4{0,0,0,0}, f32x4{0,0,0,0}, f32x4{0,0,0,0}, f32x4{0,0,0,0}};

    const float* xp = x + (size_t)row * N + k0 + g * 8;
    const unsigned short* wp = wt + k0 + g * 8;

    #pragma unroll 4
    for (int ks = 0; ks < KS_PER_SPLIT / 32; ++ks) {   // 32 iters
        float4 v0 = *(const float4*)(xp + ks * 32);
        float4 v1 = *(const float4*)(xp + ks * 32 + 4);
        bf16x8 a;
        a[0] = f2bf(v0.x); a[1] = f2bf(v0.y); a[2] = f2bf(v0.z); a[3] = f2bf(v0.w);
        a[4] = f2bf(v1.x); a[5] = f2bf(v1.y); a[6] = f2bf(v1.z); a[7] = f2bf(v1.w);
        #pragma unroll
        for (int cf = 0; cf < 4; ++cf) {
            bf16x8 b = *(const bf16x8*)(wp + (size_t)(cf * 16 + lrow) * N + ks * 32);
            acc[cf] = __builtin_amdgcn_mfma_f32_16x16x32_bf16(a, b, acc[cf], 0, 0, 0);
        }
    }
    // C/D layout: col = lane&15, row = (lane>>4)*4 + i (verified)
    float* yp = y_part + (size_t)split * N * OD + ((size_t)blockIdx.x * BM + wv * 16 + g * 4) * OD;
    #pragma unroll
    for (int cf = 0; cf < 4; ++cf) {
        #pragma unroll
        for (int i = 0; i < 4; ++i) {
            yp[i * OD + cf * 16 + lrow] = acc[cf][i];
        }
    }
}

// ---------------- y = sum over splits of y_part ----------------
__global__ __launch_bounds__(256) void reduce_y_kernel(const float4* __restrict__ y_part,
                                                       float4* __restrict__ y) {
    int i = blockIdx.x * 256 + threadIdx.x;   // 0 .. 131071 (N*OD/4)
    const int stride = N * OD / 4;
    float4 s = y_part[i];
    #pragma unroll
    for (int p = 1; p < KSPLIT; ++p) {
        float4 v = y_part[p * stride + i];
        s.x += v.x; s.y += v.y; s.z += v.z; s.w += v.w;
    }
    y[i] = s;
}

// ---------------- edge scatter: out[row[e]] += values[e]*attn[row,col] * y[col[e]] ----------------
__global__ __launch_bounds__(256) void scatter_kernel(const float* __restrict__ values,
                                                      const float* __restrict__ attn,
                                                      const int* __restrict__ row,
                                                      const int* __restrict__ col,
                                                      const float* __restrict__ y,
                                                      float* __restrict__ out) {
    const int e = blockIdx.x * 4 + (threadIdx.x >> 6);
    const int lane = threadIdx.x & 63;
    const int r = row[e];
    const int c = col[e];
    const float ev = values[e] * attn[(size_t)r * N + c];
    atomicAdd(&out[r * OD + lane], ev * y[c * OD + lane]);
}

// ---------------- finalize: norm = sqrt(sum of partials) ----------------
__global__ __launch_bounds__(256) void finalize_kernel(const float* __restrict__ part,
                                                       float* __restrict__ out_norm) {
    float s = 0.f;
    #pragma unroll
    for (int k = 0; k < NORM_BLOCKS / 256; ++k) s += part[k * 256 + threadIdx.x];
    for (int off = 32; off > 0; off >>= 1) s += __shfl_down(s, off, 64);
    __shared__ float wpart[4];
    int wid = threadIdx.x >> 6;
    if ((threadIdx.x & 63) == 0) wpart[wid] = s;
    __syncthreads();
    if (threadIdx.x == 0) *out_norm = sqrtf(wpart[0] + wpart[1] + wpart[2] + wpart[3]);
}

extern "C" void kernel_launch(void* const* d_in, const int* in_sizes, int n_in,
                              void* d_out, int out_size, void* d_ws, size_t ws_size,
                              hipStream_t stream) {
    const float* x      = (const float*)d_in[0];
    const float* attn   = (const float*)d_in[1];
    const float* weight = (const float*)d_in[2];
    const float* values = (const float*)d_in[3];
    const int*   row    = (const int*)d_in[4];
    const int*   col    = (const int*)d_in[5];
    float* out = (float*)d_out;

    char* wsb = (char*)d_ws;
    float*          norm_part = (float*)wsb;                        // 8 KB (2048 f32)
    unsigned short* wt        = (unsigned short*)(wsb + (1u << 20)); // 1 MB
    float*          y         = (float*)(wsb + (2u << 20));          // 2 MB
    float*          y_part    = (float*)(wsb + (4u << 20));          // 16 MB

    // NO in-graph memsets — fills cost ~157 us each in-graph (round 1/2 profiles).
    convert_w_kernel<<<2048, 256, 0, stream>>>(weight, wt, (float4*)out);
    gemm_kernel<<<dim3(N / BM, KSPLIT), 256, 0, stream>>>(x, wt, y_part);
    reduce_y_kernel<<<N * OD / 4 / 256, 256, 0, stream>>>((const float4*)y_part, (float4*)y);
    norm_sq_kernel<<<NORM_BLOCKS, 256, 0, stream>>>(attn, norm_part);
    scatter_kernel<<<E_EDGES / 4, 256, 0, stream>>>(values, attn, row, col, y, out);
    finalize_kernel<<<1, 256, 0, stream>>>(norm_part, out + (size_t)N * OD);
}